// Round 10
// baseline (182.150 us; speedup 1.0000x reference)
//
#include <hip/hip_runtime.h>
#include <stdint.h>

// proj = einsum('bit,ih->tbh', x, W); scan: h=relu(p+0.8h(1-y)); y=thr(h+b,1).
// B=64, K=512, T=512, H=1024 fp32. Output: final y (64x1024).
//
// R15: A direct-from-global; delete the A-LDS transpose path. R14 closed
// the books at 913 TF = the known ~912 TF ceiling of the 2-barrier
// structure (m103), with LDS reads 192KB/kt + an A round-trip
// (global->reg->convert->ds_write->ds_read) that exists only to transpose.
// But the 16x16x32 A-fragment pattern is directly loadable from global:
// for k-octet lq, lanes l15 read 16 CONSECUTIVE t (x is t-contiguous) ->
// one global_load_dword = 4 coalesced 64B segments. This round each wave
// loads its own A slice (32 dwords/lane/kt) into af[4][8], prefetched one
// kt ahead, and converts in-reg with the bit-identical split
// (f=v*64; hh=(h)f; hl=(h)(f-(float)hh)) -> same values the LDS path
// delivered. Removes per kt: writeA (2 ds_write), 8 A ds_reads/wave
// (LDS 192->128KB), the writeA tail; frees 64KB LDS (total now 64KB; P
// aliases the B dbuf). x re-reads (x2 wn-twin, x4 h-blocks) are L2-local:
// grid (b fast) puts all 4 h-blocks of batch b on XCD b%8. VGPR: af 32 +
// ah/al 32 + bh/bl 8 + addr ~25 ~= 100 < 128 -> no spill (watch
// WRITE_SIZE). End-of-kt vmcnt(0) is ~free: all in-flight VMEM was issued
// a full cluster (~4000cyc) earlier. MFMA order / B path / epilogue /
// scan unchanged -> bit-identical; absmax must hold at 0.03125.

#define NB 64
#define NK 512
#define NT 512
#define NH 1024

#define TB 256     // t per block tile
#define HB 256     // h per block tile
#define KK 32      // k per step
#define NKT (NK / KK)   // 16

typedef _Float16 h8_t __attribute__((ext_vector_type(8)));
typedef float    f4_t __attribute__((ext_vector_type(4)));

#define AS1 __attribute__((address_space(1)))
#define AS3 __attribute__((address_space(3)))

__device__ __forceinline__ void async_copy16(const void* g, void* l) {
    __builtin_amdgcn_global_load_lds((const AS1 uint32_t*)g, (AS3 uint32_t*)l, 16, 0, 0);
}

// full drain + barrier (R7/R14 proven shape; vmcnt(0) is ~free here since
// every in-flight VMEM op was issued a full MFMA cluster earlier)
__device__ __forceinline__ void wait_all_barrier() {
    __builtin_amdgcn_s_waitcnt(0);   // vmcnt(0) expcnt(0) lgkmcnt(0)
    __syncthreads();
}

// ---- W-only pre-pass: fp32 [512][1024] -> fp16 hi/lo in fragment order
__global__ __launch_bounds__(256) void split_w(
    const float* __restrict__ Wm, _Float16* __restrict__ whi,
    _Float16* __restrict__ wlo)
{
    const int tid = threadIdx.x;
    const int cq  = tid & 15;     // col quad 0..15
    const int u   = tid >> 4;     // row octet 0..15

    const int bx = blockIdx.x;    // 0..15
    const int by = blockIdx.y;    // 0..3
    const int C  = NH;
    const int col0 = bx * 64;
    const int row0 = by * 128;
    const int ktbase = by * 4;

    const float* s = Wm + (size_t)(row0 + u * 8) * C + col0 + cq * 4;

    f4_t v[8];
    #pragma unroll
    for (int j = 0; j < 8; ++j)
        v[j] = *(const f4_t*)(s + (size_t)j * C);

    const int kt = ktbase + (u >> 2);
    const int ck = u & 3;

    #pragma unroll
    for (int i = 0; i < 4; ++i) {
        h8_t hi, lo;
        #pragma unroll
        for (int j = 0; j < 8; ++j) {
            float f = v[j][i] * 64.0f;       // 2^6 pre-scale
            _Float16 hh = (_Float16)f;
            hi[j] = hh;
            lo[j] = (_Float16)(f - (float)hh);
        }
        const int col = col0 + cq * 4 + i;
        const int ckp = ck ^ ((col >> 1) & 3);
        const size_t off = ((size_t)kt * C + col) * 32 + (size_t)ckp * 8;
        *(h8_t*)(whi + off) = hi;
        *(h8_t*)(wlo + off) = lo;
    }
}

// ---------------- main fused kernel (R15: direct-from-global A) ---------------
__global__ __launch_bounds__(512, 2) void fused_main(
    const float* __restrict__ X,
    const _Float16* __restrict__ whi, const _Float16* __restrict__ wlo,
    const float* __restrict__ bias, float* __restrict__ out)
{
    // B staging only: [buf][hi/lo][HB*KK] halfs = 64 KB total.
    __shared__ __align__(16) _Float16 SB[2][2][HB * KK];
    // Epilogue P[64][256] fp32 (64 KB) aliases the whole SB region.
    float* Pf = (float*)&SB[0][0][0];

    const int tid  = threadIdx.x;
    const int lane = tid & 63;
    const int wid  = tid >> 6;     // 0..7
    const int l15  = lane & 15;
    const int lq   = lane >> 4;    // 0..3
    const int wm   = wid >> 1;     // t quarter 0..3
    const int wn   = wid & 1;      // h half 0..1

    const int b  = blockIdx.x;
    const int h0 = blockIdx.y * HB;

    // B fragment LDS offset (halfs); chunk swizzle matches prepass
    const int sw   = (l15 >> 1) & 3;
    const int boff = ((wn * 128 + l15) * 4 + (lq ^ sw)) * 8;  // + ni*512

    float hs = 0.0f, ys = 0.0f, bv = 0.0f;
    if (tid < HB) bv = bias[h0 + tid];

    const float INV_SCALE = 1.0f / 4096.0f;   // undo 2^6 x 2^6 operand scales

    auto stage_B = [&](int kt, int buf) {
        const _Float16* gb_hi = whi + ((size_t)kt * NH + h0) * KK;
        const _Float16* gb_lo = wlo + ((size_t)kt * NH + h0) * KK;
        #pragma unroll
        for (int c = 0; c < 2; ++c) {
            const int ch = tid + c * 512;
            async_copy16(gb_hi + ch * 8, &SB[buf][0][ch * 8]);
            async_copy16(gb_lo + ch * 8, &SB[buf][1][ch * 8]);
        }
    };

    // A fragment slice for this wave, loaded directly from global.
    // af[mi][j] = X[b][kt*32 + lq*8 + j][tt0 + wm*64 + mi*16 + l15]
    // Per (mi,j) wave-instr: 4 lq-groups x 16 consecutive t = 4x64B segments.
    float af[4][8];
    auto loadA = [&](int tt0_, int kt) {
        const float* g = X + ((size_t)(b * NK + kt * KK + lq * 8)) * NT
                           + tt0_ + wm * 64 + l15;
        #pragma unroll
        for (int mi = 0; mi < 4; ++mi)
            #pragma unroll
            for (int j = 0; j < 8; ++j)
                af[mi][j] = g[(size_t)j * NT + mi * 16];
    };

    h8_t ah[4], al[4];
    auto convertA = [&]() {
        #pragma unroll
        for (int mi = 0; mi < 4; ++mi)
            #pragma unroll
            for (int j = 0; j < 8; ++j) {
                float f = af[mi][j] * 64.0f;     // bit-identical split
                _Float16 hh = (_Float16)f;
                ah[mi][j] = hh;
                al[mi][j] = (_Float16)(f - (float)hh);
            }
    };

    // one ni-column: 12 MFMAs, mode-outer / mi-inner (R14 order, bit-exact)
    f4_t acc[4][8];
    auto mfma_col = [&](int cur, int ni) {
        h8_t bh = *(const h8_t*)(&SB[cur][0][boff + ni * 512]);
        h8_t bl = *(const h8_t*)(&SB[cur][1][boff + ni * 512]);
        #pragma unroll
        for (int mi = 0; mi < 4; ++mi)
            acc[mi][ni] = __builtin_amdgcn_mfma_f32_16x16x32_f16(ah[mi], bh, acc[mi][ni], 0, 0, 0);
        #pragma unroll
        for (int mi = 0; mi < 4; ++mi)
            acc[mi][ni] = __builtin_amdgcn_mfma_f32_16x16x32_f16(ah[mi], bl, acc[mi][ni], 0, 0, 0);
        #pragma unroll
        for (int mi = 0; mi < 4; ++mi)
            acc[mi][ni] = __builtin_amdgcn_mfma_f32_16x16x32_f16(al[mi], bh, acc[mi][ni], 0, 0, 0);
    };

    // prologue: first tile's B DMA + A register loads
    stage_B(0, 0);
    loadA(0, 0);

    for (int tt0 = 0; tt0 < NT; tt0 += TB) {
        #pragma unroll
        for (int mi = 0; mi < 4; ++mi)
            #pragma unroll
            for (int ni = 0; ni < 8; ++ni) {
                f4_t z = {0.f, 0.f, 0.f, 0.f};
                acc[mi][ni] = z;
            }

        wait_all_barrier();   // staged B landed block-wide; af landed

        for (int kt = 0; kt < NKT; ++kt) {
            const int cur = kt & 1;
            const bool more = (kt + 1 < NKT);

            if (more) stage_B(kt + 1, cur ^ 1);   // B DMA flies under MFMA
            convertA();                            // af from last iter: landed
            if (more) loadA(tt0, kt + 1);          // refill af; lands under MFMA

            __builtin_amdgcn_s_setprio(1);
            #pragma unroll
            for (int ni = 0; ni < 8; ++ni)
                mfma_col(cur, ni);
            __builtin_amdgcn_s_setprio(0);

            wait_all_barrier();   // ~free drain; buf swap safe for all waves
        }

        // epilogue: 4 t-subtiles x 64 rows; P[64][256] fp32 aliased on SB.
        // Swizzle: col' = col ^ (((row>>2)&1)<<4); writer key (lq&1) == reader
        // key ((m>>2)&1) since row = mi*16 + lq*4 + r. 2-way banks both sides.
        #pragma unroll 1
        for (int sub = 0; sub < 4; ++sub) {
            if (wm == sub) {
                #pragma unroll
                for (int mi = 0; mi < 4; ++mi)
                    #pragma unroll
                    for (int ni = 0; ni < 8; ++ni)
                        #pragma unroll
                        for (int r = 0; r < 4; ++r) {
                            const int row = mi * 16 + lq * 4 + r;
                            const int col = (wn * 128 + ni * 16 + l15) ^ ((lq & 1) << 4);
                            Pf[row * 256 + col] = acc[mi][ni][r] * INV_SCALE;
                        }
            }
            __syncthreads();
            if (tid < HB) {
                const int cc2 = tid;   // h within block tile, 0..255
                #pragma unroll 8
                for (int m = 0; m < 64; ++m) {
                    float p = Pf[m * 256 + (cc2 ^ (((m >> 2) & 1) << 4))];
                    float pre = p + 0.8f * hs * (1.0f - ys);
                    hs = pre > 0.0f ? pre : 0.0f;
                    float z = hs + bv;
                    ys = (z > 1.0f) ? z : 0.0f;
                }
            }
            __syncthreads();   // scan done before next sub overwrites P
        }

        // next t-tile's first stage: after the epilogue (P aliased SB; all
        // reads retired at the last __syncthreads). Latency covered by the
        // t-loop-top wait_all_barrier; af regs were dead during epilogue.
        if (tt0 + TB < NT) {
            stage_B(0, 0);
            loadA(tt0 + TB, 0);
        }
    }

    if (tid < HB)
        out[(size_t)b * NH + h0 + tid] = ys;
}

extern "C" void kernel_launch(void* const* d_in, const int* in_sizes, int n_in,
                              void* d_out, int out_size, void* d_ws, size_t ws_size,
                              hipStream_t stream) {
    const float* x    = (const float*)d_in[0];  // [64][512][512]
    const float* W    = (const float*)d_in[1];  // [512][1024]
    const float* bias = (const float*)d_in[2];  // [1024]
    float* out = (float*)d_out;

    _Float16* whi = (_Float16*)d_ws;            // 1 MB
    _Float16* wlo = whi + (size_t)NK * NH;      // 1 MB

    split_w<<<dim3(16, 4), 256, 0, stream>>>(W, whi, wlo);
    fused_main<<<dim3(NB, NH / HB), 512, 0, stream>>>(x, whi, wlo, bias, out);
}

// Round 11
// 180.349 us; speedup vs baseline: 1.0100x; 1.0100x over previous
//
#include <hip/hip_runtime.h>
#include <stdint.h>

// proj = einsum('bit,ih->tbh', x, W); scan: h=relu(p+0.8h(1-y)); y=thr(h+b,1).
// B=64, K=512, T=512, H=1024 fp32. Output: final y (64x1024).
//
// R16: kill the wn-twin A duplication. R15 (109us) showed the in-kernel
// A path costs ~14us vs R7's prepass-fed 95us: 2 waves/SIMD x (32 VMEM
// issues + ~160 convert VALU) ~= 1000 cyc/kt — and HALF of it is the
// same data twice: the 4x2 wave layout's wn twins load+convert identical
// A fragments. This round: 8x1 wave layout — each wave owns 32 t-rows x
// all 256 h (acc[2][16], same 128 regs). A loads 32->16 dwords/lane,
// convert 160->80 VALU/lane. Cost: B LDS reads double (32 b128/wave,
// 256KB/CU/kt) but spread per-col (8 waves x 2 reads/col ~380cyc vs
// ~480cyc MFMA/col -> hidden). B frag addressing unchanged (swizzle key
// (l15>>1)&3 is ni-invariant); epilogue writer key (row bit2 = lq&1)
// preserved; per-element MFMA order (mode-outer per col, kt asc)
// unchanged -> bit-identical; absmax must hold at 0.03125.
// Everything else = R15: direct-from-global A, B DMA dbuf, W-only
// prepass (2MB ws), P[64][256] aliased on SB, single drain+barrier/kt.

#define NB 64
#define NK 512
#define NT 512
#define NH 1024

#define TB 256     // t per block tile
#define HB 256     // h per block tile
#define KK 32      // k per step
#define NKT (NK / KK)   // 16

typedef _Float16 h8_t __attribute__((ext_vector_type(8)));
typedef float    f4_t __attribute__((ext_vector_type(4)));

#define AS1 __attribute__((address_space(1)))
#define AS3 __attribute__((address_space(3)))

__device__ __forceinline__ void async_copy16(const void* g, void* l) {
    __builtin_amdgcn_global_load_lds((const AS1 uint32_t*)g, (AS3 uint32_t*)l, 16, 0, 0);
}

// full drain + barrier (proven shape; vmcnt(0) is ~free: all in-flight
// VMEM was issued a full MFMA cluster (~3900cyc) earlier)
__device__ __forceinline__ void wait_all_barrier() {
    __builtin_amdgcn_s_waitcnt(0);   // vmcnt(0) expcnt(0) lgkmcnt(0)
    __syncthreads();
}

// ---- W-only pre-pass: fp32 [512][1024] -> fp16 hi/lo in fragment order
__global__ __launch_bounds__(256) void split_w(
    const float* __restrict__ Wm, _Float16* __restrict__ whi,
    _Float16* __restrict__ wlo)
{
    const int tid = threadIdx.x;
    const int cq  = tid & 15;     // col quad 0..15
    const int u   = tid >> 4;     // row octet 0..15

    const int bx = blockIdx.x;    // 0..15
    const int by = blockIdx.y;    // 0..3
    const int C  = NH;
    const int col0 = bx * 64;
    const int row0 = by * 128;
    const int ktbase = by * 4;

    const float* s = Wm + (size_t)(row0 + u * 8) * C + col0 + cq * 4;

    f4_t v[8];
    #pragma unroll
    for (int j = 0; j < 8; ++j)
        v[j] = *(const f4_t*)(s + (size_t)j * C);

    const int kt = ktbase + (u >> 2);
    const int ck = u & 3;

    #pragma unroll
    for (int i = 0; i < 4; ++i) {
        h8_t hi, lo;
        #pragma unroll
        for (int j = 0; j < 8; ++j) {
            float f = v[j][i] * 64.0f;       // 2^6 pre-scale
            _Float16 hh = (_Float16)f;
            hi[j] = hh;
            lo[j] = (_Float16)(f - (float)hh);
        }
        const int col = col0 + cq * 4 + i;
        const int ckp = ck ^ ((col >> 1) & 3);
        const size_t off = ((size_t)kt * C + col) * 32 + (size_t)ckp * 8;
        *(h8_t*)(whi + off) = hi;
        *(h8_t*)(wlo + off) = lo;
    }
}

// ---------------- main fused kernel (R16: 8x1 waves, no A dup) ---------------
__global__ __launch_bounds__(512, 2) void fused_main(
    const float* __restrict__ X,
    const _Float16* __restrict__ whi, const _Float16* __restrict__ wlo,
    const float* __restrict__ bias, float* __restrict__ out)
{
    // B staging only: [buf][hi/lo][HB*KK] halfs = 64 KB total.
    __shared__ __align__(16) _Float16 SB[2][2][HB * KK];
    // Epilogue P[64][256] fp32 (64 KB) aliases the whole SB region.
    float* Pf = (float*)&SB[0][0][0];

    const int tid  = threadIdx.x;
    const int lane = tid & 63;
    const int wid  = tid >> 6;     // 0..7 = wm (t octant, 32 rows each)
    const int l15  = lane & 15;
    const int lq   = lane >> 4;    // 0..3

    const int b  = blockIdx.x;
    const int h0 = blockIdx.y * HB;

    // B fragment LDS offset (halfs); chunk swizzle matches prepass.
    // ni-invariant: (ni*16 + l15) bits 1-2 == l15 bits 1-2.
    const int sw   = (l15 >> 1) & 3;
    const int boff = (l15 * 4 + (lq ^ sw)) * 8;   // + ni*512, ni 0..15

    float hs = 0.0f, ys = 0.0f, bv = 0.0f;
    if (tid < HB) bv = bias[h0 + tid];

    const float INV_SCALE = 1.0f / 4096.0f;   // undo 2^6 x 2^6 operand scales

    auto stage_B = [&](int kt, int buf) {
        const _Float16* gb_hi = whi + ((size_t)kt * NH + h0) * KK;
        const _Float16* gb_lo = wlo + ((size_t)kt * NH + h0) * KK;
        #pragma unroll
        for (int c = 0; c < 2; ++c) {
            const int ch = tid + c * 512;
            async_copy16(gb_hi + ch * 8, &SB[buf][0][ch * 8]);
            async_copy16(gb_lo + ch * 8, &SB[buf][1][ch * 8]);
        }
    };

    // A fragment slice for this wave, loaded directly from global (no dup).
    // af[mi][j] = X[b][kt*32 + lq*8 + j][tt0 + wid*32 + mi*16 + l15]
    float af[2][8];
    auto loadA = [&](int tt0_, int kt) {
        const float* g = X + ((size_t)(b * NK + kt * KK + lq * 8)) * NT
                           + tt0_ + wid * 32 + l15;
        #pragma unroll
        for (int mi = 0; mi < 2; ++mi)
            #pragma unroll
            for (int j = 0; j < 8; ++j)
                af[mi][j] = g[(size_t)j * NT + mi * 16];
    };

    h8_t ah[2], al[2];
    auto convertA = [&]() {
        #pragma unroll
        for (int mi = 0; mi < 2; ++mi)
            #pragma unroll
            for (int j = 0; j < 8; ++j) {
                float f = af[mi][j] * 64.0f;     // bit-identical split
                _Float16 hh = (_Float16)f;
                ah[mi][j] = hh;
                al[mi][j] = (_Float16)(f - (float)hh);
            }
    };

    // one ni-column: 6 MFMAs, mode-outer / mi-inner (bit-exact per-acc order)
    f4_t acc[2][16];
    auto mfma_col = [&](int cur, int ni) {
        h8_t bh = *(const h8_t*)(&SB[cur][0][boff + ni * 512]);
        h8_t bl = *(const h8_t*)(&SB[cur][1][boff + ni * 512]);
        #pragma unroll
        for (int mi = 0; mi < 2; ++mi)
            acc[mi][ni] = __builtin_amdgcn_mfma_f32_16x16x32_f16(ah[mi], bh, acc[mi][ni], 0, 0, 0);
        #pragma unroll
        for (int mi = 0; mi < 2; ++mi)
            acc[mi][ni] = __builtin_amdgcn_mfma_f32_16x16x32_f16(ah[mi], bl, acc[mi][ni], 0, 0, 0);
        #pragma unroll
        for (int mi = 0; mi < 2; ++mi)
            acc[mi][ni] = __builtin_amdgcn_mfma_f32_16x16x32_f16(al[mi], bh, acc[mi][ni], 0, 0, 0);
    };

    // prologue: first tile's B DMA + A register loads
    stage_B(0, 0);
    loadA(0, 0);

    for (int tt0 = 0; tt0 < NT; tt0 += TB) {
        #pragma unroll
        for (int mi = 0; mi < 2; ++mi)
            #pragma unroll
            for (int ni = 0; ni < 16; ++ni) {
                f4_t z = {0.f, 0.f, 0.f, 0.f};
                acc[mi][ni] = z;
            }

        wait_all_barrier();   // staged B landed block-wide; af landed

        for (int kt = 0; kt < NKT; ++kt) {
            const int cur = kt & 1;
            const bool more = (kt + 1 < NKT);

            if (more) stage_B(kt + 1, cur ^ 1);   // B DMA flies under MFMA
            convertA();                            // af from last iter: landed
            if (more) loadA(tt0, kt + 1);          // refill af; lands under MFMA

            __builtin_amdgcn_s_setprio(1);
            #pragma unroll
            for (int ni = 0; ni < 16; ++ni)
                mfma_col(cur, ni);
            __builtin_amdgcn_s_setprio(0);

            wait_all_barrier();   // ~free drain; buf swap safe for all waves
        }

        // epilogue: 4 t-subtiles x 64 rows; P[64][256] fp32 aliased on SB.
        // Rows [sub*64, sub*64+64) come from waves wid = 2*sub, 2*sub+1.
        // Swizzle col' = col ^ (((row>>2)&1)<<4); writer key (lq&1) ==
        // reader key ((m>>2)&1) since rloc = (wid&1)*32 + mi*16 + lq*4 + r.
        #pragma unroll 1
        for (int sub = 0; sub < 4; ++sub) {
            if ((wid >> 1) == sub) {
                #pragma unroll
                for (int mi = 0; mi < 2; ++mi)
                    #pragma unroll
                    for (int ni = 0; ni < 16; ++ni)
                        #pragma unroll
                        for (int r = 0; r < 4; ++r) {
                            const int rloc = (wid & 1) * 32 + mi * 16 + lq * 4 + r;
                            const int col  = (ni * 16 + l15) ^ ((lq & 1) << 4);
                            Pf[rloc * 256 + col] = acc[mi][ni][r] * INV_SCALE;
                        }
            }
            __syncthreads();
            if (tid < HB) {
                const int cc2 = tid;   // h within block tile, 0..255
                #pragma unroll 8
                for (int m = 0; m < 64; ++m) {
                    float p = Pf[m * 256 + (cc2 ^ (((m >> 2) & 1) << 4))];
                    float pre = p + 0.8f * hs * (1.0f - ys);
                    hs = pre > 0.0f ? pre : 0.0f;
                    float z = hs + bv;
                    ys = (z > 1.0f) ? z : 0.0f;
                }
            }
            __syncthreads();   // scan done before next sub overwrites P
        }

        // next t-tile's first stage: after the epilogue (P aliased SB; all
        // reads retired at the last __syncthreads). Latency covered by the
        // t-loop-top wait_all_barrier; af regs were dead during epilogue.
        if (tt0 + TB < NT) {
            stage_B(0, 0);
            loadA(tt0 + TB, 0);
        }
    }

    if (tid < HB)
        out[(size_t)b * NH + h0 + tid] = ys;
}

extern "C" void kernel_launch(void* const* d_in, const int* in_sizes, int n_in,
                              void* d_out, int out_size, void* d_ws, size_t ws_size,
                              hipStream_t stream) {
    const float* x    = (const float*)d_in[0];  // [64][512][512]
    const float* W    = (const float*)d_in[1];  // [512][1024]
    const float* bias = (const float*)d_in[2];  // [1024]
    float* out = (float*)d_out;

    _Float16* whi = (_Float16*)d_ws;            // 1 MB
    _Float16* wlo = whi + (size_t)NK * NH;      // 1 MB

    split_w<<<dim3(16, 4), 256, 0, stream>>>(W, whi, wlo);
    fused_main<<<dim3(NB, NH / HB), 512, 0, stream>>>(x, whi, wlo, bias, out);
}

// Round 12
// 177.483 us; speedup vs baseline: 1.0263x; 1.0161x over previous
//
#include <hip/hip_runtime.h>
#include <stdint.h>

// proj = einsum('bit,ih->tbh', x, W); scan: h=relu(p+0.8h(1-y)); y=thr(h+b,1).
// B=64, K=512, T=512, H=1024 fp32. Output: final y (64x1024).
//
// R17: phases + counted vmcnt — the one documented cell not yet run.
// Session matrix: 2ph+drain0 (R7/13/15/16) = 41% MfmaUtil wall (~950 TF,
// the known plain-HIP 2-phase ceiling); phases+drain0 (R9) = neutral
// (matches m218-V1); counted-no-phases (R10) = confounded regression
// (m131 predicts neutral). m201/m218 say the GAIN is phases AND counted
// TOGETHER. This round, on R16's geometry (8x1 waves, A direct-from-
// global, HB=256 so FETCH stays 49MB):
//  - B in a 3-ring (3 x 32KB; ring[kt%3]); P[64][256] aliases ring0+ring1.
//  - per kt: 4 phases x 4 ni-cols: {ds_read 8 b128 + issue region ->
//    s_barrier -> lgkmcnt(0) -> setprio(1) -> 24 MFMA -> setprio(0) ->
//    s_barrier}. loadA(kt+1) split P0/P1; stage_B(kt+2) in P2.
//  - ONLY vmem wait: counted vmcnt(4) at kt boundary (drains loadA(kt+1),
//    leaves stage_B(kt+2) flying; stage_B(kt) is ~20 ops old -> landed).
//    Ring recycle safe: each phase's lgkmcnt(0) retires its reads.
//  - prologue issue order loadA -> stage_B(0) -> stage_B(1) makes the
//    boundary vmcnt(4) leave exactly stage_B(1). Verified for steady
//    state and tail (kt=15 issues nothing; vmcnt trivially satisfied).
// No sched_barrier(0) (R10's mistake); all barriers unconditional;
// compiler still tracks every register load (correctness rails).
// Per-element MFMA order unchanged -> bit-identical; absmax 0.03125.

#define NB 64
#define NK 512
#define NT 512
#define NH 1024

#define TB 256     // t per block tile
#define HB 256     // h per block tile
#define KK 32      // k per step
#define NKT (NK / KK)   // 16

typedef _Float16 h8_t __attribute__((ext_vector_type(8)));
typedef float    f4_t __attribute__((ext_vector_type(4)));

#define AS1 __attribute__((address_space(1)))
#define AS3 __attribute__((address_space(3)))

__device__ __forceinline__ void async_copy16(const void* g, void* l) {
    __builtin_amdgcn_global_load_lds((const AS1 uint32_t*)g, (AS3 uint32_t*)l, 16, 0, 0);
}

__device__ __forceinline__ void wait_all_barrier() {
    __builtin_amdgcn_s_waitcnt(0);   // vmcnt(0) expcnt(0) lgkmcnt(0)
    __syncthreads();
}

// ---- W-only pre-pass: fp32 [512][1024] -> fp16 hi/lo in fragment order
__global__ __launch_bounds__(256) void split_w(
    const float* __restrict__ Wm, _Float16* __restrict__ whi,
    _Float16* __restrict__ wlo)
{
    const int tid = threadIdx.x;
    const int cq  = tid & 15;     // col quad 0..15
    const int u   = tid >> 4;     // row octet 0..15

    const int bx = blockIdx.x;    // 0..15
    const int by = blockIdx.y;    // 0..3
    const int C  = NH;
    const int col0 = bx * 64;
    const int row0 = by * 128;
    const int ktbase = by * 4;

    const float* s = Wm + (size_t)(row0 + u * 8) * C + col0 + cq * 4;

    f4_t v[8];
    #pragma unroll
    for (int j = 0; j < 8; ++j)
        v[j] = *(const f4_t*)(s + (size_t)j * C);

    const int kt = ktbase + (u >> 2);
    const int ck = u & 3;

    #pragma unroll
    for (int i = 0; i < 4; ++i) {
        h8_t hi, lo;
        #pragma unroll
        for (int j = 0; j < 8; ++j) {
            float f = v[j][i] * 64.0f;       // 2^6 pre-scale
            _Float16 hh = (_Float16)f;
            hi[j] = hh;
            lo[j] = (_Float16)(f - (float)hh);
        }
        const int col = col0 + cq * 4 + i;
        const int ckp = ck ^ ((col >> 1) & 3);
        const size_t off = ((size_t)kt * C + col) * 32 + (size_t)ckp * 8;
        *(h8_t*)(whi + off) = hi;
        *(h8_t*)(wlo + off) = lo;
    }
}

// ---------------- main fused kernel (R17: 4-phase + counted vmcnt) ------------
__global__ __launch_bounds__(512, 2) void fused_main(
    const float* __restrict__ X,
    const _Float16* __restrict__ whi, const _Float16* __restrict__ wlo,
    const float* __restrict__ bias, float* __restrict__ out)
{
    // B ring: 3 buffers x [hi/lo][8192] halfs = 3 x 32 KB = 96 KB.
    __shared__ __align__(16) _Float16 RB[3][2][HB * KK];
    // Epilogue P[64][256] fp32 (64 KB) aliases ring0 + ring1 (contiguous).
    float* Pf = (float*)&RB[0][0][0];

    const int tid  = threadIdx.x;
    const int lane = tid & 63;
    const int wid  = tid >> 6;     // 0..7 = t octant (32 rows each)
    const int l15  = lane & 15;
    const int lq   = lane >> 4;    // 0..3

    const int b  = blockIdx.x;
    const int h0 = blockIdx.y * HB;

    // B fragment LDS offset (halfs); chunk swizzle matches prepass.
    const int sw   = (l15 >> 1) & 3;
    const int boff = (l15 * 4 + (lq ^ sw)) * 8;   // + ni*512, ni 0..15

    float hs = 0.0f, ys = 0.0f, bv = 0.0f;
    if (tid < HB) bv = bias[h0 + tid];

    const float INV_SCALE = 1.0f / 4096.0f;   // undo 2^6 x 2^6 operand scales

    auto stage_B = [&](int kt, int r) {       // 4 VMEM instrs / thread
        const _Float16* gb_hi = whi + ((size_t)kt * NH + h0) * KK;
        const _Float16* gb_lo = wlo + ((size_t)kt * NH + h0) * KK;
        #pragma unroll
        for (int c = 0; c < 2; ++c) {
            const int ch = tid + c * 512;
            async_copy16(gb_hi + ch * 8, &RB[r][0][ch * 8]);
            async_copy16(gb_lo + ch * 8, &RB[r][1][ch * 8]);
        }
    };

    // A fragment slice, direct from global (no dup across waves).
    // af[mi][j] = X[b][kt*32 + lq*8 + j][tt0 + wid*32 + mi*16 + l15]
    float af[2][8];
    auto loadA_half = [&](int tt0_, int kt, int half) {   // 8 VMEM instrs
        const float* g = X + ((size_t)(b * NK + kt * KK + lq * 8)) * NT
                           + tt0_ + wid * 32 + l15;
        const int mi = half;
        #pragma unroll
        for (int j = 0; j < 8; ++j)
            af[mi][j] = g[(size_t)j * NT + mi * 16];
    };

    h8_t ah[2], al[2];
    auto convertA = [&]() {
        #pragma unroll
        for (int mi = 0; mi < 2; ++mi)
            #pragma unroll
            for (int j = 0; j < 8; ++j) {
                float f = af[mi][j] * 64.0f;     // bit-identical split
                _Float16 hh = (_Float16)f;
                ah[mi][j] = hh;
                al[mi][j] = (_Float16)(f - (float)hh);
            }
    };

    f4_t acc[2][16];

    // prologue (issue order matters for the boundary vmcnt(4) ledger):
    // loadA(0) [16] -> stage_B(0,r0) [4] -> stage_B(1,r1) [4]
    loadA_half(0, 0, 0); loadA_half(0, 0, 1);
    stage_B(0, 0);
    stage_B(1, 1);

    for (int tt0 = 0; tt0 < NT; tt0 += TB) {
        #pragma unroll
        for (int mi = 0; mi < 2; ++mi)
            #pragma unroll
            for (int ni = 0; ni < 16; ++ni) {
                f4_t z = {0.f, 0.f, 0.f, 0.f};
                acc[mi][ni] = z;
            }

        // t-tile top boundary: counted drain (leaves stage_B(1) flying)
        asm volatile("s_waitcnt vmcnt(4)" ::: "memory");
        __builtin_amdgcn_s_barrier();

        for (int kt = 0; kt < NKT; ++kt) {
            const int r = kt % 3;
            const bool moreA  = (kt + 1 < NKT);
            const bool moreB  = (kt + 2 < NKT);
            const _Float16* bh_base = &RB[r][0][0];
            const _Float16* bl_base = &RB[r][1][0];

            convertA();   // af(kt): drained by the boundary vmcnt(4)

            h8_t bh[4], bl[4];
            #pragma unroll
            for (int p = 0; p < 4; ++p) {
                // ---- issue region ----
                if (p == 0 && moreA) loadA_half(tt0, kt + 1, 0);   // 8 VMEM
                if (p == 1 && moreA) loadA_half(tt0, kt + 1, 1);   // 8 VMEM
                if (p == 2 && moreB) stage_B(kt + 2, (kt + 2) % 3); // 4 VMEM
                #pragma unroll
                for (int c = 0; c < 4; ++c) {
                    bh[c] = *(const h8_t*)(bh_base + boff + (p * 4 + c) * 512);
                    bl[c] = *(const h8_t*)(bl_base + boff + (p * 4 + c) * 512);
                }
                // ---- phase open ----
                __builtin_amdgcn_s_barrier();
                asm volatile("s_waitcnt lgkmcnt(0)" ::: "memory");
                __builtin_amdgcn_s_setprio(1);
                #pragma unroll
                for (int c = 0; c < 4; ++c) {
                    const int ni = p * 4 + c;
                    // mode-outer / mi-inner: per-acc chain hh -> hl -> lh
                    #pragma unroll
                    for (int mi = 0; mi < 2; ++mi)
                        acc[mi][ni] = __builtin_amdgcn_mfma_f32_16x16x32_f16(ah[mi], bh[c], acc[mi][ni], 0, 0, 0);
                    #pragma unroll
                    for (int mi = 0; mi < 2; ++mi)
                        acc[mi][ni] = __builtin_amdgcn_mfma_f32_16x16x32_f16(ah[mi], bl[c], acc[mi][ni], 0, 0, 0);
                    #pragma unroll
                    for (int mi = 0; mi < 2; ++mi)
                        acc[mi][ni] = __builtin_amdgcn_mfma_f32_16x16x32_f16(al[mi], bh[c], acc[mi][ni], 0, 0, 0);
                }
                __builtin_amdgcn_s_setprio(0);
                // ---- phase close / kt boundary ----
                if (p == 3) {
                    // counted: drains loadA(kt+1); stage_B(kt+2) stays in
                    // flight. stage_B(kt+1) is ~20 ops old -> landed.
                    asm volatile("s_waitcnt vmcnt(4)" ::: "memory");
                }
                __builtin_amdgcn_s_barrier();
            }
        }

        // epilogue: full drain once per t-tile (vmem is empty here anyway)
        wait_all_barrier();

        // P[64][256] fp32 on ring0+ring1. Rows [sub*64, sub*64+64) come
        // from waves wid = 2*sub, 2*sub+1. Swizzle col' = col ^
        // (((row>>2)&1)<<4); writer key (lq&1) == reader key ((m>>2)&1).
        #pragma unroll 1
        for (int sub = 0; sub < 4; ++sub) {
            if ((wid >> 1) == sub) {
                #pragma unroll
                for (int mi = 0; mi < 2; ++mi)
                    #pragma unroll
                    for (int ni = 0; ni < 16; ++ni)
                        #pragma unroll
                        for (int r2 = 0; r2 < 4; ++r2) {
                            const int rloc = (wid & 1) * 32 + mi * 16 + lq * 4 + r2;
                            const int col  = (ni * 16 + l15) ^ ((lq & 1) << 4);
                            Pf[rloc * 256 + col] = acc[mi][ni][r2] * INV_SCALE;
                        }
            }
            __syncthreads();
            if (tid < HB) {
                const int cc2 = tid;   // h within block tile, 0..255
                #pragma unroll 8
                for (int m = 0; m < 64; ++m) {
                    float p = Pf[m * 256 + (cc2 ^ (((m >> 2) & 1) << 4))];
                    float pre = p + 0.8f * hs * (1.0f - ys);
                    hs = pre > 0.0f ? pre : 0.0f;
                    float z = hs + bv;
                    ys = (z > 1.0f) ? z : 0.0f;
                }
            }
            __syncthreads();   // scan done before next sub overwrites P
        }

        // next t-tile prologue (after P is dead). Issue order per ledger:
        // loadA [16] -> stage_B(0,r0) [4] -> stage_B(1,r1) [4].
        if (tt0 + TB < NT) {
            loadA_half(tt0 + TB, 0, 0); loadA_half(tt0 + TB, 0, 1);
            stage_B(0, 0);
            stage_B(1, 1);
        }
    }

    if (tid < HB)
        out[(size_t)b * NH + h0 + tid] = ys;
}

extern "C" void kernel_launch(void* const* d_in, const int* in_sizes, int n_in,
                              void* d_out, int out_size, void* d_ws, size_t ws_size,
                              hipStream_t stream) {
    const float* x    = (const float*)d_in[0];  // [64][512][512]
    const float* W    = (const float*)d_in[1];  // [512][1024]
    const float* bias = (const float*)d_in[2];  // [1024]
    float* out = (float*)d_out;

    _Float16* whi = (_Float16*)d_ws;            // 1 MB
    _Float16* wlo = whi + (size_t)NK * NH;      // 1 MB

    split_w<<<dim3(16, 4), 256, 0, stream>>>(W, whi, wlo);
    fused_main<<<dim3(NB, NH / HB), 512, 0, stream>>>(x, whi, wlo, bias, out);
}